// Round 1
// baseline (97.877 us; speedup 1.0000x reference)
//
#include <hip/hip_runtime.h>
#include <stdint.h>

// Problem constants (from reference): B=4, QL=256, CL=512, XD=ED=DIM=128, YD=16
#define Bc   4
#define QLc  256
#define CLc  512
#define Dc   128
#define YDc  16
#define NROW (Bc * QLc)     // 1024 (b,q) rows
#define NFP  (Bc * CLc)     // 2048 (b,c) rows

// ---------------- Threefry-2x32, 20 rounds (exact JAX semantics) -------------
__device__ __forceinline__ uint32_t rotl32(uint32_t x, int d) {
  return (x << d) | (x >> (32 - d));
}

__device__ __forceinline__ void tf2x32(uint32_t k0, uint32_t k1, uint32_t x0,
                                       uint32_t x1, uint32_t& o0, uint32_t& o1) {
  const uint32_t k2 = k0 ^ k1 ^ 0x1BD11BDAu;
  uint32_t v0 = x0 + k0, v1 = x1 + k1;
  v0 += v1; v1 = rotl32(v1, 13); v1 ^= v0;
  v0 += v1; v1 = rotl32(v1, 15); v1 ^= v0;
  v0 += v1; v1 = rotl32(v1, 26); v1 ^= v0;
  v0 += v1; v1 = rotl32(v1, 6);  v1 ^= v0;
  v0 += k1; v1 += k2 + 1u;
  v0 += v1; v1 = rotl32(v1, 17); v1 ^= v0;
  v0 += v1; v1 = rotl32(v1, 29); v1 ^= v0;
  v0 += v1; v1 = rotl32(v1, 16); v1 ^= v0;
  v0 += v1; v1 = rotl32(v1, 24); v1 ^= v0;
  v0 += k2; v1 += k0 + 2u;
  v0 += v1; v1 = rotl32(v1, 13); v1 ^= v0;
  v0 += v1; v1 = rotl32(v1, 15); v1 ^= v0;
  v0 += v1; v1 = rotl32(v1, 26); v1 ^= v0;
  v0 += v1; v1 = rotl32(v1, 6);  v1 ^= v0;
  v0 += k0; v1 += k1 + 3u;
  v0 += v1; v1 = rotl32(v1, 17); v1 ^= v0;
  v0 += v1; v1 = rotl32(v1, 29); v1 ^= v0;
  v0 += v1; v1 = rotl32(v1, 16); v1 ^= v0;
  v0 += v1; v1 = rotl32(v1, 24); v1 ^= v0;
  v0 += k1; v1 += k2 + 4u;
  v0 += v1; v1 = rotl32(v1, 13); v1 ^= v0;
  v0 += v1; v1 = rotl32(v1, 15); v1 ^= v0;
  v0 += v1; v1 = rotl32(v1, 26); v1 ^= v0;
  v0 += v1; v1 = rotl32(v1, 6);  v1 ^= v0;
  v0 += k2; v1 += k0 + 5u;
  o0 = v0; o1 = v1;
}

// jax.random.key(1) -> data (0,1). Partitionable (fold-like) split:
// keys[i] = tf(key, (0, i)) both words. kcat = keys[0], keps = keys[1].
__device__ __forceinline__ void subkeys(uint32_t& ck0, uint32_t& ck1,
                                        uint32_t& ek0, uint32_t& ek1) {
  tf2x32(0u, 1u, 0u, 0u, ck0, ck1);   // kcat
  tf2x32(0u, 1u, 0u, 1u, ek0, ek1);   // keps
}

// Partitionable random_bits: bits[i] = o0 ^ o1 of tf(key, (hi(i)=0, lo(i)=i))
__device__ __forceinline__ uint32_t rbits(uint32_t k0, uint32_t k1, uint32_t i) {
  uint32_t o0, o1;
  tf2x32(k0, k1, 0u, i, o0, o1);
  return o0 ^ o1;
}

// JAX uniform [0,1): ((bits>>9)|0x3f800000) bitcast - 1.0
__device__ __forceinline__ float bits_to_unit(uint32_t bits) {
  return __uint_as_float((bits >> 9) | 0x3f800000u) - 1.0f;
}

// Giles single-precision erfinv (matches XLA's polynomial approach to ~1e-6 rel)
__device__ __forceinline__ float erfinv_f(float x) {
  float w = -__logf((1.0f - x) * (1.0f + x));
  // use precise logf to be safe near |x|->1
  w = -logf((1.0f - x) * (1.0f + x));
  float p;
  if (w < 5.0f) {
    w -= 2.5f;
    p = 2.81022636e-08f;
    p = fmaf(p, w, 3.43273939e-07f);
    p = fmaf(p, w, -3.5233877e-06f);
    p = fmaf(p, w, -4.39150654e-06f);
    p = fmaf(p, w, 0.00021858087f);
    p = fmaf(p, w, -0.00125372503f);
    p = fmaf(p, w, -0.00417768164f);
    p = fmaf(p, w, 0.246640727f);
    p = fmaf(p, w, 1.50140941f);
  } else {
    w = sqrtf(w) - 3.0f;
    p = -0.000200214257f;
    p = fmaf(p, w, 0.000100950558f);
    p = fmaf(p, w, 0.00134934322f);
    p = fmaf(p, w, -0.00367342844f);
    p = fmaf(p, w, 0.00573950773f);
    p = fmaf(p, w, -0.0076224613f);
    p = fmaf(p, w, 0.00943887047f);
    p = fmaf(p, w, 1.00167406f);
    p = fmaf(p, w, 2.83297682f);
  }
  return p * x;
}

// -----------------------------------------------------------------------------
// Kernel 1: blocks 0..255   -> fp rows (8 rows/block): fp = f_embed @ W1f
//           blocks 256..383 -> qp rows (8 rows/block): qp = q @ W1q
//           blocks 384..1407-> gumbel-argmax per (b,q) row -> idx
// -----------------------------------------------------------------------------
__global__ __launch_bounds__(128) void k_pre(
    const float* __restrict__ q, const float* __restrict__ f,
    const float* __restrict__ logits, const float* __restrict__ W1q,
    const float* __restrict__ W1f, float* __restrict__ ws_fp,
    float* __restrict__ ws_qp, int* __restrict__ ws_idx) {
  const int blk = blockIdx.x;
  const int tid = threadIdx.x;
  __shared__ float sx[8][Dc];
  __shared__ float sv[128];
  __shared__ int   si[128];

  if (blk < 384) {
    const bool is_f = (blk < 256);
    const int row0 = is_f ? blk * 8 : (blk - 256) * 8;
    const float* X = is_f ? f : q;
    const float* W = is_f ? W1f : W1q;
    float* O = is_f ? ws_fp : ws_qp;
#pragma unroll
    for (int r = 0; r < 8; ++r) sx[r][tid] = X[(row0 + r) * Dc + tid];
    __syncthreads();
    float acc[8] = {0.f, 0.f, 0.f, 0.f, 0.f, 0.f, 0.f, 0.f};
    for (int h = 0; h < Dc; ++h) {
      const float w = W[h * Dc + tid];
#pragma unroll
      for (int r = 0; r < 8; ++r) acc[r] = fmaf(sx[r][h], w, acc[r]);
    }
#pragma unroll
    for (int r = 0; r < 8; ++r) O[(row0 + r) * Dc + tid] = acc[r];
  } else {
    // ---- categorical: argmax_c (gumbel + logits) over CL=512, first-max ties
    const int bq = blk - 384;                 // 0..1023
    uint32_t ck0, ck1, ek0, ek1;
    subkeys(ck0, ck1, ek0, ek1);
    float best = -3.4e38f;
    int bi = 1 << 30;
#pragma unroll
    for (int j = 0; j < 4; ++j) {
      const int c = tid + j * 128;
      const uint32_t i = (uint32_t)(bq * CLc + c);     // row-major (b,q,c) index
      const uint32_t bits = rbits(ck0, ck1, i);
      float fl = bits_to_unit(bits);
      float u = fmaxf(1.17549435e-38f, fl);            // JAX minval=tiny path
      float g = -logf(-logf(u));                       // gumbel
      float val = g + logits[i];
      if (val > best || (val == best && c < bi)) { best = val; bi = c; }
    }
    sv[tid] = best; si[tid] = bi;
    __syncthreads();
    for (int s = 64; s > 0; s >>= 1) {
      if (tid < s) {
        const float v2 = sv[tid + s];
        const int i2 = si[tid + s];
        if (v2 > sv[tid] || (v2 == sv[tid] && i2 < si[tid])) {
          sv[tid] = v2; si[tid] = i2;
        }
      }
      __syncthreads();
    }
    if (tid == 0) ws_idx[bq] = si[0];
  }
}

// -----------------------------------------------------------------------------
// Kernel 2: 128 blocks x 128 threads, 8 (b,q) rows per block.
// h1 = relu(qp + fp[idx] + b1); h2 = relu(h1@W2 + b2); out = h2@Wout + bout
// mu=out[:16], s=out[16:32]; sigma=softplus(max(-15,s)); y = mu + sigma*eps
// -----------------------------------------------------------------------------
__global__ __launch_bounds__(128) void k_mlp(
    const float* __restrict__ ws_fp, const float* __restrict__ ws_qp,
    const int* __restrict__ ws_idx, const float* __restrict__ b1,
    const float* __restrict__ W2, const float* __restrict__ b2,
    const float* __restrict__ Wout, const float* __restrict__ bout,
    float* __restrict__ out) {
  const int blk = blockIdx.x;
  const int tid = threadIdx.x;
  const int row0 = blk * 8;
  __shared__ float sh[8][Dc];
  __shared__ float so[8][32];
  __shared__ int sidx[8];

  if (tid < 8) sidx[tid] = ws_idx[row0 + tid];
  __syncthreads();

  // ---- layer 1 (per-row gather of fp)
  const float bias1 = b1[tid];
#pragma unroll
  for (int r = 0; r < 8; ++r) {
    const int row = row0 + r;
    const int b = row >> 8;                    // QL = 256
    const int c = sidx[r];
    const float v = ws_qp[row * Dc + tid] + ws_fp[(b * CLc + c) * Dc + tid] + bias1;
    sh[r][tid] = fmaxf(v, 0.0f);
  }
  __syncthreads();

  // ---- layer 2: h2[k] = relu(b2[k] + sum_h h1[h]*W2[h,k])
  float acc[8];
  const float bias2 = b2[tid];
#pragma unroll
  for (int r = 0; r < 8; ++r) acc[r] = bias2;
  for (int h = 0; h < Dc; ++h) {
    const float w = W2[h * Dc + tid];
#pragma unroll
    for (int r = 0; r < 8; ++r) acc[r] = fmaf(sh[r][h], w, acc[r]);
  }
  __syncthreads();
#pragma unroll
  for (int r = 0; r < 8; ++r) sh[r][tid] = fmaxf(acc[r], 0.0f);
  __syncthreads();

  // ---- output layer: 32 cols; thread (rg=tid>>5, k=tid&31) does rows 2rg,2rg+1
  {
    const int k = tid & 31, rg = tid >> 5;
    const int r0 = rg * 2, r1 = rg * 2 + 1;
    float o0 = bout[k], o1 = o0;
    for (int h = 0; h < Dc; ++h) {
      const float w = Wout[h * 32 + k];
      o0 = fmaf(sh[r0][h], w, o0);
      o1 = fmaf(sh[r1][h], w, o1);
    }
    so[r0][k] = o0; so[r1][k] = o1;
  }
  __syncthreads();

  // ---- sample: thread (r=tid>>4, y=tid&15)
  {
    const int r = tid >> 4, y = tid & 15;
    const int row = row0 + r;
    const float mu = so[r][y];
    const float s = so[r][16 + y];
    const float sm = fmaxf(-15.0f, s);
    // softplus = logaddexp(x,0) = max(x,0) + log1p(exp(-|x|))
    const float sigma = fmaxf(sm, 0.0f) + log1pf(expf(-fabsf(sm)));

    uint32_t ck0, ck1, ek0, ek1;
    subkeys(ck0, ck1, ek0, ek1);
    const uint32_t i = (uint32_t)(row * YDc + y);      // row-major (b,q,y)
    const uint32_t bits = rbits(ek0, ek1, i);
    const float fl = bits_to_unit(bits);
    // JAX normal: u = max(lo, fl*(hi-lo)+lo), lo=nextafter(-1,0), (hi-lo)->2.0f
    const float lo = -0.999999940395355224609375f;
    const float prod = __fmul_rn(fl, 2.0f);
    const float u = fmaxf(lo, __fadd_rn(prod, lo));
    const float eps = 1.4142135623730951f * erfinv_f(u);
    out[row * YDc + y] = mu + sigma * eps;
  }
}

// -----------------------------------------------------------------------------
extern "C" void kernel_launch(void* const* d_in, const int* in_sizes, int n_in,
                              void* d_out, int out_size, void* d_ws, size_t ws_size,
                              hipStream_t stream) {
  const float* q      = (const float*)d_in[0];
  const float* f      = (const float*)d_in[1];
  const float* logits = (const float*)d_in[2];
  const float* W1q    = (const float*)d_in[3];
  const float* W1f    = (const float*)d_in[4];
  const float* b1     = (const float*)d_in[5];
  const float* W2     = (const float*)d_in[6];
  const float* b2     = (const float*)d_in[7];
  const float* Wout   = (const float*)d_in[8];
  const float* bout   = (const float*)d_in[9];
  float* out = (float*)d_out;

  float* ws_fp  = (float*)d_ws;                 // 2048*128 floats
  float* ws_qp  = ws_fp + NFP * Dc;             // 1024*128 floats
  int*   ws_idx = (int*)(ws_qp + NROW * Dc);    // 1024 ints

  k_pre<<<dim3(256 + 128 + NROW), dim3(128), 0, stream>>>(
      q, f, logits, W1q, W1f, ws_fp, ws_qp, ws_idx);
  k_mlp<<<dim3(NROW / 8), dim3(128), 0, stream>>>(
      ws_fp, ws_qp, ws_idx, b1, W2, b2, Wout, bout, out);
}

// Round 2
// 84.593 us; speedup vs baseline: 1.1570x; 1.1570x over previous
//
#include <hip/hip_runtime.h>
#include <stdint.h>

// Problem constants: B=4, QL=256, CL=512, XD=ED=DIM=128, YD=16
#define Bc   4
#define QLc  256
#define CLc  512
#define Dc   128
#define YDc  16
#define NROW (Bc * QLc)     // 1024 (b,q) rows

// ---------------- Threefry-2x32, 20 rounds (exact JAX semantics) -------------
__device__ __forceinline__ uint32_t rotl32(uint32_t x, int d) {
  return (x << d) | (x >> (32 - d));
}

__device__ __forceinline__ void tf2x32(uint32_t k0, uint32_t k1, uint32_t x0,
                                       uint32_t x1, uint32_t& o0, uint32_t& o1) {
  const uint32_t k2 = k0 ^ k1 ^ 0x1BD11BDAu;
  uint32_t v0 = x0 + k0, v1 = x1 + k1;
  v0 += v1; v1 = rotl32(v1, 13); v1 ^= v0;
  v0 += v1; v1 = rotl32(v1, 15); v1 ^= v0;
  v0 += v1; v1 = rotl32(v1, 26); v1 ^= v0;
  v0 += v1; v1 = rotl32(v1, 6);  v1 ^= v0;
  v0 += k1; v1 += k2 + 1u;
  v0 += v1; v1 = rotl32(v1, 17); v1 ^= v0;
  v0 += v1; v1 = rotl32(v1, 29); v1 ^= v0;
  v0 += v1; v1 = rotl32(v1, 16); v1 ^= v0;
  v0 += v1; v1 = rotl32(v1, 24); v1 ^= v0;
  v0 += k2; v1 += k0 + 2u;
  v0 += v1; v1 = rotl32(v1, 13); v1 ^= v0;
  v0 += v1; v1 = rotl32(v1, 15); v1 ^= v0;
  v0 += v1; v1 = rotl32(v1, 26); v1 ^= v0;
  v0 += v1; v1 = rotl32(v1, 6);  v1 ^= v0;
  v0 += k0; v1 += k1 + 3u;
  v0 += v1; v1 = rotl32(v1, 17); v1 ^= v0;
  v0 += v1; v1 = rotl32(v1, 29); v1 ^= v0;
  v0 += v1; v1 = rotl32(v1, 16); v1 ^= v0;
  v0 += v1; v1 = rotl32(v1, 24); v1 ^= v0;
  v0 += k1; v1 += k2 + 4u;
  v0 += v1; v1 = rotl32(v1, 13); v1 ^= v0;
  v0 += v1; v1 = rotl32(v1, 15); v1 ^= v0;
  v0 += v1; v1 = rotl32(v1, 26); v1 ^= v0;
  v0 += v1; v1 = rotl32(v1, 6);  v1 ^= v0;
  v0 += k2; v1 += k0 + 5u;
  o0 = v0; o1 = v1;
}

// jax.random.key(1) -> data (0,1). Partitionable split: keys[i] = tf(key,(0,i)).
__device__ __forceinline__ void subkeys(uint32_t& ck0, uint32_t& ck1,
                                        uint32_t& ek0, uint32_t& ek1) {
  tf2x32(0u, 1u, 0u, 0u, ck0, ck1);   // kcat
  tf2x32(0u, 1u, 0u, 1u, ek0, ek1);   // keps
}

__device__ __forceinline__ uint32_t rbits(uint32_t k0, uint32_t k1, uint32_t i) {
  uint32_t o0, o1;
  tf2x32(k0, k1, 0u, i, o0, o1);
  return o0 ^ o1;
}

// JAX uniform [0,1): ((bits>>9)|0x3f800000) bitcast - 1.0
__device__ __forceinline__ float bits_to_unit(uint32_t bits) {
  return __uint_as_float((bits >> 9) | 0x3f800000u) - 1.0f;
}

// Giles single-precision erfinv (validated round 1: absmax 7.8e-3)
__device__ __forceinline__ float erfinv_f(float x) {
  float w = -logf((1.0f - x) * (1.0f + x));
  float p;
  if (w < 5.0f) {
    w -= 2.5f;
    p = 2.81022636e-08f;
    p = fmaf(p, w, 3.43273939e-07f);
    p = fmaf(p, w, -3.5233877e-06f);
    p = fmaf(p, w, -4.39150654e-06f);
    p = fmaf(p, w, 0.00021858087f);
    p = fmaf(p, w, -0.00125372503f);
    p = fmaf(p, w, -0.00417768164f);
    p = fmaf(p, w, 0.246640727f);
    p = fmaf(p, w, 1.50140941f);
  } else {
    w = sqrtf(w) - 3.0f;
    p = -0.000200214257f;
    p = fmaf(p, w, 0.000100950558f);
    p = fmaf(p, w, 0.00134934322f);
    p = fmaf(p, w, -0.00367342844f);
    p = fmaf(p, w, 0.00573950773f);
    p = fmaf(p, w, -0.0076224613f);
    p = fmaf(p, w, 0.00943887047f);
    p = fmaf(p, w, 1.00167406f);
    p = fmaf(p, w, 2.83297682f);
  }
  return p * x;
}

// -----------------------------------------------------------------------------
// Fully fused: 512 blocks x 256 threads, 2 (b,q) rows per block.
// Per row: gumbel-argmax(512) -> idx; qp = q@W1q; fp = f[idx]@W1f (selected row
// only!); h1=relu(qp+fp+b1); h2=relu(h1@W2+b2); out=h2@Wout+bout; sample.
// No workspace, single launch.
// -----------------------------------------------------------------------------
__global__ __launch_bounds__(256) void k_fused(
    const float* __restrict__ q, const float* __restrict__ f,
    const float* __restrict__ logits, const float* __restrict__ W1q,
    const float* __restrict__ W1f, const float* __restrict__ b1,
    const float* __restrict__ W2, const float* __restrict__ b2,
    const float* __restrict__ Wout, const float* __restrict__ bout,
    float* __restrict__ out) {
  const int tid = threadIdx.x;
  const int r   = tid >> 7;            // 0..1 : which row of the pair
  const int l   = tid & 127;           // 0..127 : lane within row
  const int row = blockIdx.x * 2 + r;  // 0..1023 global (b,q) row
  const int b   = row >> 8;            // QL = 256

  __shared__ float sx[2][Dc];          // staged input row (q, then f[idx])
  __shared__ float sh[2][Dc];          // hidden activations
  __shared__ float sv[256];
  __shared__ int   si[256];
  __shared__ float spart[2][4][32];
  __shared__ float so[2][32];
  __shared__ int   sc[2];

  // Early-issue the q element this thread owns (consumed after the argmax).
  const float qv = q[row * Dc + l];

  uint32_t ck0, ck1, ek0, ek1;
  subkeys(ck0, ck1, ek0, ek1);

  // ---- 1. gumbel-argmax over this row's 512 logits (first-max ties) --------
  float best = -3.4e38f;
  int bi = 1 << 30;
#pragma unroll
  for (int j = 0; j < 4; ++j) {
    const int c = l + j * 128;
    const uint32_t i = (uint32_t)(row * CLc + c);      // row-major (b,q,c)
    const uint32_t bits = rbits(ck0, ck1, i);
    const float fl = bits_to_unit(bits);
    const float u = fmaxf(1.17549435e-38f, fl);        // JAX minval=tiny
    const float g = -logf(-logf(u));                   // gumbel
    const float val = g + logits[i];
    if (val > best || (val == best && c < bi)) { best = val; bi = c; }
  }
  sv[tid] = best; si[tid] = bi;
  __syncthreads();
  for (int s = 64; s > 0; s >>= 1) {
    if (l < s) {
      const int a0 = r * 128 + l, a1 = a0 + s;
      const float v2 = sv[a1];
      const int i2 = si[a1];
      if (v2 > sv[a0] || (v2 == sv[a0] && i2 < si[a0])) {
        sv[a0] = v2; si[a0] = i2;
      }
    }
    __syncthreads();
  }
  if (l == 0) sc[r] = si[r * 128];

  // ---- 2. qp = q_row @ W1q (thread -> output column l) ---------------------
  sx[r][l] = qv;
  __syncthreads();
  float acc1 = 0.0f;
  for (int h = 0; h < Dc; ++h) acc1 = fmaf(sx[r][h], W1q[h * Dc + l], acc1);

  // ---- 3. fp = f_embed[b, idx] @ W1f (selected row only) -------------------
  const int csel = sc[r];
  const float fv = f[(b * CLc + csel) * Dc + l];
  __syncthreads();                      // all sx reads done before overwrite
  sx[r][l] = fv;
  __syncthreads();
  float accf = 0.0f;
  for (int h = 0; h < Dc; ++h) accf = fmaf(sx[r][h], W1f[h * Dc + l], accf);

  // ---- 4. h1 = relu(qp + fp + b1) ------------------------------------------
  sh[r][l] = fmaxf(acc1 + accf + b1[l], 0.0f);
  __syncthreads();

  // ---- 5. h2 = relu(h1 @ W2 + b2) ------------------------------------------
  float acc2 = b2[l];
  for (int h = 0; h < Dc; ++h) acc2 = fmaf(sh[r][h], W2[h * Dc + l], acc2);
  __syncthreads();
  sh[r][l] = fmaxf(acc2, 0.0f);
  __syncthreads();

  // ---- 6. out = h2 @ Wout + bout (32 cols, split-K by 4 groups of 32) ------
  {
    const int k  = tid & 31;
    const int rr = (tid >> 5) & 1;
    const int g  = tid >> 6;            // 0..3
    float p = 0.0f;
#pragma unroll
    for (int hh = 0; hh < 32; ++hh) {
      const int h = g * 32 + hh;
      p = fmaf(sh[rr][h], Wout[h * 32 + k], p);
    }
    spart[rr][g][k] = p;
  }
  __syncthreads();
  if (tid < 64) {
    const int rr = tid >> 5, k = tid & 31;
    so[rr][k] = bout[k] + spart[rr][0][k] + spart[rr][1][k] +
                spart[rr][2][k] + spart[rr][3][k];
  }
  __syncthreads();

  // ---- 7. sample: sigma = softplus(max(-15,s)); y = mu + sigma*eps ---------
  if (tid < 32) {
    const int rr = tid >> 4, y = tid & 15;
    const int orow = blockIdx.x * 2 + rr;
    const float mu = so[rr][y];
    const float s  = so[rr][16 + y];
    const float sm = fmaxf(-15.0f, s);
    const float sigma = fmaxf(sm, 0.0f) + log1pf(expf(-fabsf(sm)));

    const uint32_t i = (uint32_t)(orow * YDc + y);     // row-major (b,q,y)
    const uint32_t bits = rbits(ek0, ek1, i);
    const float fl = bits_to_unit(bits);
    const float lo = -0.999999940395355224609375f;     // nextafter(-1,0)
    const float prod = __fmul_rn(fl, 2.0f);
    const float u = fmaxf(lo, __fadd_rn(prod, lo));
    const float eps = 1.4142135623730951f * erfinv_f(u);
    out[orow * YDc + y] = mu + sigma * eps;
  }
}

// -----------------------------------------------------------------------------
extern "C" void kernel_launch(void* const* d_in, const int* in_sizes, int n_in,
                              void* d_out, int out_size, void* d_ws, size_t ws_size,
                              hipStream_t stream) {
  const float* q      = (const float*)d_in[0];
  const float* f      = (const float*)d_in[1];
  const float* logits = (const float*)d_in[2];
  const float* W1q    = (const float*)d_in[3];
  const float* W1f    = (const float*)d_in[4];
  const float* b1     = (const float*)d_in[5];
  const float* W2     = (const float*)d_in[6];
  const float* b2     = (const float*)d_in[7];
  const float* Wout   = (const float*)d_in[8];
  const float* bout   = (const float*)d_in[9];
  float* out = (float*)d_out;

  k_fused<<<dim3(NROW / 2), dim3(256), 0, stream>>>(
      q, f, logits, W1q, W1f, b1, W2, b2, Wout, bout, out);
}